// Round 4
// baseline (269.097 us; speedup 1.0000x reference)
//
#include <hip/hip_runtime.h>
#include <hip/hip_bf16.h>

// (B, LIN, E, D, N) = (32, 2048, 512, 512, 2)
#define L_SZ 2048
#define E_SZ 512
#define D_SZ 512
#define ND   1024
// ws layout: dec_proj (32*512 f32) | Bt (512*512 bf16, [n][k]) | scores (32*2048 f32)
#define WS_DEC_OFF 0
#define WS_BT_OFF  (32*512*4)
#define WS_SC_OFF  (32*512*4 + 512*512*2)

typedef unsigned short ushort_t;
typedef unsigned int   uint_t;
typedef __attribute__((ext_vector_type(8))) short short8;   // 8 bf16 (MFMA A/B frag)
typedef __attribute__((ext_vector_type(4))) float floatx4;  // MFMA C/D frag
typedef __attribute__((ext_vector_type(4))) float fvec4;    // clang-native float4

__device__ __forceinline__ ushort_t f2bf(float f) {
  uint_t u = __builtin_bit_cast(uint_t, f);
  u += 0x7fffu + ((u >> 16) & 1u);
  return (ushort_t)(u >> 16);
}

__device__ __forceinline__ float fast_tanh(float x) {
  float e = __expf(2.0f * x);
  return 1.0f - 2.0f * __builtin_amdgcn_rcpf(e + 1.0f);
}

// Non-temporal 16B load (emits global_load_dwordx4 ... nt): enc is streamed
// exactly once -> do NOT let it allocate in L2. Keeps Bt (512 KB/XCD,
// re-read by every block) L2-hot. Must use clang-native ext_vector type:
// __builtin_nontemporal_load rejects HIP_vector_type.
__device__ __forceinline__ fvec4 ntload4(const float* p) {
  return __builtin_nontemporal_load((const fvec4*)p);
}

// async 16B global->LDS DMA; lptr must be wave-uniform, HW deposits lane i at lptr + 16*i
__device__ __forceinline__ void dma16(const ushort_t* g, ushort_t* l) {
  __builtin_amdgcn_global_load_lds(
      (const __attribute__((address_space(1))) uint_t*)(const void*)g,
      (__attribute__((address_space(3))) uint_t*)(void*)l,
      16, 0, 0);
}

// ---------------------------------------------------------------------------
// Prep, 512 blocks:
//  blocks 0..255  : dec_proj[b][d] (b=blk>>3, d-tile=blk&7), k split 4-way + LDS reduce
//  blocks 256..511: Bt[n][k] = bf16(W1[1024+k][n]) via 32x32 LDS transpose tiles
// ---------------------------------------------------------------------------
__global__ __launch_bounds__(256) void prep_k(const float* __restrict__ dh,
                                              const float* __restrict__ W1,
                                              const float* __restrict__ b1,
                                              float* __restrict__ dec,
                                              ushort_t* __restrict__ Bt) {
  int blk = blockIdx.x, t = threadIdx.x;
  if (blk < 256) {
    int b = blk >> 3, d = (blk & 7) * 64 + (t & 63);
    int q = t >> 6;
    __shared__ float red[4][64];
    const float* dfb = dh + b * ND;
    float s = 0.f;
    #pragma unroll 8
    for (int k = q * 256; k < q * 256 + 256; k++)
      s = fmaf(dfb[k], W1[k * D_SZ + d], s);
    red[q][t & 63] = s;
    __syncthreads();
    if (q == 0)
      dec[b * D_SZ + d] = red[0][t] + red[1][t] + red[2][t] + red[3][t] + b1[d];
  } else {
    int tid = blk - 256;
    int tk = (tid >> 4) * 32, tn = (tid & 15) * 32;
    __shared__ float tile[32][33];
    int cc = t & 31, r8 = t >> 5;
    #pragma unroll
    for (int p = 0; p < 4; p++) {
      int r = r8 + p * 8;
      tile[r][cc] = W1[(ND + tk + r) * D_SZ + tn + cc];
    }
    __syncthreads();
    #pragma unroll
    for (int p = 0; p < 4; p++) {
      int nn = r8 + p * 8;
      Bt[(tn + nn) * E_SZ + tk + cc] = f2bf(tile[cc][nn]);
    }
  }
}

// ---------------------------------------------------------------------------
// Main: WG = 512 threads (8 waves) = 64 rows (one b,l-tile) x ALL 512 cols.
// K = 512 in 8 windows of BK=64. Wave w owns cols [w*64, w*64+64):
// 4 mt x 4 nt tiles of 16x16x32, acc[4][4] = 64 AGPRs.
//
// Traffic model (round-2/3 theory): each block re-reads ALL of Bt (512 KB) ->
// 512 MB/invocation. The enc stream (134 MB, read once) cycles one full L2
// per XCD per block-generation, evicting Bt -> Bt was being served by L3 at
// ~6.5 TB/s = the measured wall. Fix: enc loads are NON-TEMPORAL (nt flag,
// no L2 allocate) so Bt stays L2-resident; Bt re-reads then ride L2.
// Schedule unchanged from round 2 (one-variable experiment).
// ---------------------------------------------------------------------------
__global__ __launch_bounds__(512, 2) void main_k(const float* __restrict__ enc,
                                                 const ushort_t* __restrict__ Bt,
                                                 const float* __restrict__ dec,
                                                 const float* __restrict__ w2,
                                                 float* __restrict__ scores) {
  const int b  = blockIdx.y;
  const int l0 = blockIdx.x * 64;
  const int t  = threadIdx.x;            // 0..511
  const int wave = t >> 6, lane = t & 63;
  const int col = lane & 15, quad = lane >> 4;

  __shared__ __align__(16) ushort_t Bs[2][512 * 64];  // 2 x 64 KB
  __shared__ __align__(16) ushort_t As[2][64 * 64];   // 2 x 8 KB
  __shared__ float s_sc[64];

  if (t < 64) s_sc[t] = 0.f;

  floatx4 acc[4][4];
  #pragma unroll
  for (int mt = 0; mt < 4; mt++)
    #pragma unroll
    for (int nt = 0; nt < 4; nt++)
      acc[mt][nt] = (floatx4){0.f, 0.f, 0.f, 0.f};

  const float* arow = enc + (size_t)(b * L_SZ + l0) * E_SZ;

  // A: thread t owns chunk t: row am, chunk ac (8 floats -> 8 bf16 = 16B)
  const int am = t >> 3, ac = t & 7;
  const float* aptr = arow + am * E_SZ + ac * 8;
  const int awoff = am * 64 + ((ac ^ (am & 7)) << 3);

  // B DMA source mapping: slot s = wave*512 + j*64 + lane; n = s>>3; c = (s&7)^(n&7)
  // (source pre-XOR-permuted so the linear deposit lands in the swizzled layout)
  const int bn0 = wave * 64 + (lane >> 3);            // row for j=0
  const int bc0 = (lane & 7) ^ ((lane >> 3) & 7);     // chunk, constant over j
  const ushort_t* bptr0 = Bt + bn0 * E_SZ + bc0 * 8;

  // ---- prologue: stage window 0 into buffer 0 ----
  fvec4 pa = ntload4(aptr);
  fvec4 pb = ntload4(aptr + 4);
  #pragma unroll
  for (int j = 0; j < 8; j++)
    dma16(bptr0 + j * 8 * E_SZ, &Bs[0][wave * 4096 + j * 512]);
  {
    union { short8 v; __hip_bfloat162 h[4]; } pk;
    pk.h[0] = __float22bfloat162_rn(make_float2(pa.x, pa.y));
    pk.h[1] = __float22bfloat162_rn(make_float2(pa.z, pa.w));
    pk.h[2] = __float22bfloat162_rn(make_float2(pb.x, pb.y));
    pk.h[3] = __float22bfloat162_rn(make_float2(pb.z, pb.w));
    *(short8*)&As[0][awoff] = pk.v;
  }
  asm volatile("s_waitcnt vmcnt(0) lgkmcnt(0)" ::: "memory");
  __builtin_amdgcn_s_barrier();
  __builtin_amdgcn_sched_barrier(0);

  #pragma unroll 1
  for (int kw = 0; kw < 8; kw++) {
    const ushort_t* Acur = &As[kw & 1][0];
    const ushort_t* Bcur = &Bs[kw & 1][0];

    // ---- issue window kw+1 loads FIRST (consumed only after next barrier) ----
    if (kw < 7) {
      const float* ap = aptr + (kw + 1) * 64;
      pa = ntload4(ap);                               // 2 nt global loads -> regs
      pb = ntload4(ap + 4);
      const ushort_t* bp = bptr0 + (kw + 1) * 64;
      ushort_t* bld = &Bs[(kw + 1) & 1][wave * 4096];
      #pragma unroll
      for (int j = 0; j < 8; j++)                     // 8 async DMAs -> Bs[nxt]
        dma16(bp + j * 8 * E_SZ, bld + j * 512);
    }

    // ---- MFMA on buffers staged LAST window: LDS-only, no global waits ----
    #pragma unroll
    for (int ks = 0; ks < 2; ks++) {
      short8 af[4], bfr[4];
      #pragma unroll
      for (int mt = 0; mt < 4; mt++) {
        int m = mt * 16 + col;
        af[mt] = *(const short8*)&Acur[m * 64 + ((((ks << 2) + quad) ^ (m & 7)) << 3)];
      }
      #pragma unroll
      for (int nt = 0; nt < 4; nt++) {
        int n = wave * 64 + nt * 16 + col;
        bfr[nt] = *(const short8*)&Bcur[n * 64 + ((((ks << 2) + quad) ^ (n & 7)) << 3)];
      }
      #pragma unroll
      for (int mt = 0; mt < 4; mt++)
        #pragma unroll
        for (int nt = 0; nt < 4; nt++)
          acc[mt][nt] = __builtin_amdgcn_mfma_f32_16x16x32_bf16(af[mt], bfr[nt], acc[mt][nt], 0, 0, 0);
    }

    // ---- cvt A(kw+1) regs -> As[nxt] (compiler waits vmcnt(8): DMAs stay out) ----
    if (kw < 7) {
      union { short8 v; __hip_bfloat162 h[4]; } pk;
      pk.h[0] = __float22bfloat162_rn(make_float2(pa.x, pa.y));
      pk.h[1] = __float22bfloat162_rn(make_float2(pa.z, pa.w));
      pk.h[2] = __float22bfloat162_rn(make_float2(pb.x, pb.y));
      pk.h[3] = __float22bfloat162_rn(make_float2(pb.z, pb.w));
      *(short8*)&As[(kw + 1) & 1][awoff] = pk.v;
    }

    // ---- window boundary: drained ops are ~a full window old ----
    asm volatile("s_waitcnt vmcnt(0) lgkmcnt(0)" ::: "memory");
    __builtin_amdgcn_s_barrier();
    __builtin_amdgcn_sched_barrier(0);
  }

  // ---- epilogue: tanh(acc + dec) . w2, reduced over n ----
  // C/D: D[row=quad*4+r][col] => m = mt*16+quad*4+r, n = wave*64+nt*16+col
  const float* decb = dec + b * D_SZ;
  float sums[4][4];
  #pragma unroll
  for (int mt = 0; mt < 4; mt++)
    #pragma unroll
    for (int r = 0; r < 4; r++) sums[mt][r] = 0.f;

  #pragma unroll
  for (int nt = 0; nt < 4; nt++) {
    int n = wave * 64 + nt * 16 + col;
    float dv = decb[n];
    float wv = w2[n];
    #pragma unroll
    for (int mt = 0; mt < 4; mt++)
      #pragma unroll
      for (int r = 0; r < 4; r++)
        sums[mt][r] += fast_tanh(acc[mt][nt][r] + dv) * wv;
  }
  #pragma unroll
  for (int mt = 0; mt < 4; mt++) {
    #pragma unroll
    for (int r = 0; r < 4; r++) {
      float v = sums[mt][r];
      v += __shfl_xor(v, 1, 16);
      v += __shfl_xor(v, 2, 16);
      v += __shfl_xor(v, 4, 16);
      v += __shfl_xor(v, 8, 16);
      if (col == 0) atomicAdd(&s_sc[mt * 16 + quad * 4 + r], v);  // 8 waves/row
    }
  }
  __syncthreads();
  if (t < 64) scores[b * L_SZ + l0 + t] = s_sc[t];
}

// ---------------------------------------------------------------------------
// Softmax: one WG (1024 threads) per batch row of 2048.
// ---------------------------------------------------------------------------
__global__ __launch_bounds__(1024) void softmax_k(const float* __restrict__ sc,
                                                  float* __restrict__ out) {
  int b = blockIdx.x, t = threadIdx.x;
  int wave = t >> 6, lane = t & 63;
  __shared__ float redm[16], reds[16];
  const float* row = sc + b * L_SZ;
  float v0 = row[t], v1 = row[t + 1024];
  float mx = fmaxf(v0, v1);
  #pragma unroll
  for (int off = 32; off >= 1; off >>= 1) mx = fmaxf(mx, __shfl_xor(mx, off, 64));
  if (lane == 0) redm[wave] = mx;
  __syncthreads();
  float m = redm[0];
  #pragma unroll
  for (int i = 1; i < 16; i++) m = fmaxf(m, redm[i]);
  v0 = __expf(v0 - m);
  v1 = __expf(v1 - m);
  float s = v0 + v1;
  #pragma unroll
  for (int off = 32; off >= 1; off >>= 1) s += __shfl_xor(s, off, 64);
  if (lane == 0) reds[wave] = s;
  __syncthreads();
  float sum = reds[0];
  #pragma unroll
  for (int i = 1; i < 16; i++) sum += reds[i];
  float inv = 1.0f / sum;
  out[b * L_SZ + t]        = v0 * inv;
  out[b * L_SZ + t + 1024] = v1 * inv;
}

extern "C" void kernel_launch(void* const* d_in, const int* in_sizes, int n_in,
                              void* d_out, int out_size, void* d_ws, size_t ws_size,
                              hipStream_t stream) {
  const float* d_hidden = (const float*)d_in[0];   // (32, 2, 512)
  const float* enc      = (const float*)d_in[1];   // (32, 2048, 512)
  const float* W1       = (const float*)d_in[2];   // (1536, 512)
  const float* b1       = (const float*)d_in[3];   // (512,)
  const float* w2       = (const float*)d_in[4];   // (512,)
  float* out = (float*)d_out;                      // (32, 2048)

  char* ws = (char*)d_ws;
  float*    dec = (float*)(ws + WS_DEC_OFF);
  ushort_t* Bt  = (ushort_t*)(ws + WS_BT_OFF);
  float*    sc  = (float*)(ws + WS_SC_OFF);

  prep_k<<<512, 256, 0, stream>>>(d_hidden, W1, b1, dec, Bt);
  main_k<<<dim3(32, 32), 512, 0, stream>>>(enc, Bt, dec, w2, sc);
  softmax_k<<<32, 1024, 0, stream>>>(sc, out);
}

// Round 5
// 255.670 us; speedup vs baseline: 1.0525x; 1.0525x over previous
//
#include <hip/hip_runtime.h>
#include <hip/hip_bf16.h>

// (B, LIN, E, D, N) = (32, 2048, 512, 512, 2)
#define L_SZ 2048
#define E_SZ 512
#define D_SZ 512
#define ND   1024
// ws layout: dec_proj (32*512 f32) | Bt (512*512 bf16, [n][k]) | scores (32*2048 f32)
#define WS_DEC_OFF 0
#define WS_BT_OFF  (32*512*4)
#define WS_SC_OFF  (32*512*4 + 512*512*2)

typedef unsigned short ushort_t;
typedef unsigned int   uint_t;
typedef __attribute__((ext_vector_type(8))) short short8;    // 8 bf16 (MFMA A/B frag)
typedef __attribute__((ext_vector_type(4))) short short4_t;  // 4 bf16 (8B ds_write)
typedef __attribute__((ext_vector_type(4))) float floatx4;   // MFMA C/D frag

__device__ __forceinline__ ushort_t f2bf(float f) {
  uint_t u = __builtin_bit_cast(uint_t, f);
  u += 0x7fffu + ((u >> 16) & 1u);
  return (ushort_t)(u >> 16);
}

__device__ __forceinline__ float fast_tanh(float x) {
  float e = __expf(2.0f * x);
  return 1.0f - 2.0f * __builtin_amdgcn_rcpf(e + 1.0f);
}

// async 16B global->LDS DMA; lptr must be wave-uniform, HW deposits lane i at lptr + 16*i
__device__ __forceinline__ void dma16(const ushort_t* g, ushort_t* l) {
  __builtin_amdgcn_global_load_lds(
      (const __attribute__((address_space(1))) uint_t*)(const void*)g,
      (__attribute__((address_space(3))) uint_t*)(void*)l,
      16, 0, 0);
}

// ---------------------------------------------------------------------------
// Prep, 512 blocks:
//  blocks 0..255  : dec_proj[b][d] (b=blk>>3, d-tile=blk&7), k split 4-way + LDS reduce
//  blocks 256..511: Bt[n][k] = bf16(W1[1024+k][n]) via 32x32 LDS transpose tiles
// ---------------------------------------------------------------------------
__global__ __launch_bounds__(256) void prep_k(const float* __restrict__ dh,
                                              const float* __restrict__ W1,
                                              const float* __restrict__ b1,
                                              float* __restrict__ dec,
                                              ushort_t* __restrict__ Bt) {
  int blk = blockIdx.x, t = threadIdx.x;
  if (blk < 256) {
    int b = blk >> 3, d = (blk & 7) * 64 + (t & 63);
    int q = t >> 6;
    __shared__ float red[4][64];
    const float* dfb = dh + b * ND;
    float s = 0.f;
    #pragma unroll 8
    for (int k = q * 256; k < q * 256 + 256; k++)
      s = fmaf(dfb[k], W1[k * D_SZ + d], s);
    red[q][t & 63] = s;
    __syncthreads();
    if (q == 0)
      dec[b * D_SZ + d] = red[0][t] + red[1][t] + red[2][t] + red[3][t] + b1[d];
  } else {
    int tid = blk - 256;
    int tk = (tid >> 4) * 32, tn = (tid & 15) * 32;
    __shared__ float tile[32][33];
    int cc = t & 31, r8 = t >> 5;
    #pragma unroll
    for (int p = 0; p < 4; p++) {
      int r = r8 + p * 8;
      tile[r][cc] = W1[(ND + tk + r) * D_SZ + tn + cc];
    }
    __syncthreads();
    #pragma unroll
    for (int p = 0; p < 4; p++) {
      int nn = r8 + p * 8;
      Bt[(tn + nn) * E_SZ + tk + cc] = f2bf(tile[cc][nn]);
    }
  }
}

// ---------------------------------------------------------------------------
// Main, restructured (round 5):
// WG = 1024 threads (16 waves) = 128 rows (BM=128) x ALL 512 cols.
// Grid = (16 l-tiles, 32 b) = 512 blocks -> each Bt byte re-read 512x (was
// 1024x): Bt traffic 512->256 MB, total ~390 MB. 16 waves/CU restores the
// r0-class TLP that covered barrier drains (r2's 8-wave/CU pipeline stalled).
//
// Wave w: rows mbase=(w>>3)*64 + [0,64), cols nbase=(w&7)*64 + [0,64):
// 4mt x 4nt tiles of 16x16x32, acc[4][4] = 64 VGPRs.
// K = 512 in 16 windows of BK=32. Rows in LDS are 64B -> a wave's frag read
// (m 16 rows x quad 16B) covers a dense 1KB region: conflict-free WITHOUT
// swizzle; B-DMA source mapping is linear (no XOR).
// Both operands double-buffered (Bs 2x32KB, As 2x8KB = 80.5 KB), loads issued
// one window ahead, ONE raw barrier per window (vmcnt drains 1-window-old ops).
// __launch_bounds__(1024,4) caps VGPR at 128 so all 16 waves co-reside.
// ---------------------------------------------------------------------------
__global__ __launch_bounds__(1024, 4) void main_k(const float* __restrict__ enc,
                                                  const ushort_t* __restrict__ Bt,
                                                  const float* __restrict__ dec,
                                                  const float* __restrict__ w2,
                                                  float* __restrict__ scores) {
  const int b  = blockIdx.y;
  const int l0 = blockIdx.x * 128;
  const int t  = threadIdx.x;            // 0..1023
  const int wave = t >> 6, lane = t & 63;
  const int col = lane & 15, quad = lane >> 4;
  const int mbase = (wave >> 3) * 64;    // 0 / 64
  const int nbase = (wave & 7) * 64;     // 0..448

  __shared__ __align__(16) ushort_t Bs[2][512 * 32];  // 2 x 32 KB, [n][k] rows of 64B
  __shared__ __align__(16) ushort_t As[2][128 * 32];  // 2 x 8 KB,  [m][k] rows of 64B
  __shared__ float s_sc[128];

  if (t < 128) s_sc[t] = 0.f;

  floatx4 acc[4][4];
  #pragma unroll
  for (int mt = 0; mt < 4; mt++)
    #pragma unroll
    for (int nt = 0; nt < 4; nt++)
      acc[mt][nt] = (floatx4){0.f, 0.f, 0.f, 0.f};

  const float* arow = enc + (size_t)(b * L_SZ + l0) * E_SZ;

  // A staging: thread t owns row ar = t>>3, k-chunk akc = t&7 (4 floats -> 4 bf16, 8B)
  const int ar = t >> 3, akc = t & 7;
  const float* aptr = arow + ar * E_SZ + akc * 4;
  const int awoff = ar * 32 + akc * 4;               // ushort index

  // B staging: slot s covers Bs row n = s>>2, 16B k-chunk kc = s&3.
  // Wave w deposits slots [w*128, w*128+128) via 2 DMAs (wave-uniform lptr).
  const int s0 = wave * 128 + lane;                  // j=0 slot
  const ushort_t* bsrc0 = Bt + (s0 >> 2) * E_SZ + (s0 & 3) * 8;
  const int s1 = s0 + 64;                            // j=1 slot
  const ushort_t* bsrc1 = Bt + (s1 >> 2) * E_SZ + (s1 & 3) * 8;

  // ---- prologue: stage window 0 into buffer 0 ----
  float4 pa = *(const float4*)aptr;
  dma16(bsrc0, &Bs[0][wave * 1024]);
  dma16(bsrc1, &Bs[0][wave * 1024 + 512]);
  {
    union { short4_t v; __hip_bfloat162 h[2]; } pk;
    pk.h[0] = __float22bfloat162_rn(make_float2(pa.x, pa.y));
    pk.h[1] = __float22bfloat162_rn(make_float2(pa.z, pa.w));
    *(short4_t*)&As[0][awoff] = pk.v;
  }
  asm volatile("s_waitcnt vmcnt(0) lgkmcnt(0)" ::: "memory");
  __builtin_amdgcn_s_barrier();
  __builtin_amdgcn_sched_barrier(0);

  #pragma unroll 1
  for (int kw = 0; kw < 16; kw++) {
    const ushort_t* Acur = &As[kw & 1][0];
    const ushort_t* Bcur = &Bs[kw & 1][0];

    // ---- issue window kw+1 loads FIRST (consumed only after next barrier) ----
    if (kw < 15) {
      pa = *(const float4*)(aptr + (kw + 1) * 32);
      ushort_t* bld = &Bs[(kw + 1) & 1][wave * 1024];
      dma16(bsrc0 + (kw + 1) * 32, bld);
      dma16(bsrc1 + (kw + 1) * 32, bld + 512);
    }

    // ---- MFMA on buffers staged LAST window: LDS-only, no global waits ----
    short8 af[4], bfr[4];
    #pragma unroll
    for (int mt = 0; mt < 4; mt++)
      af[mt] = *(const short8*)&Acur[(mbase + mt * 16 + col) * 32 + quad * 8];
    #pragma unroll
    for (int nt = 0; nt < 4; nt++)
      bfr[nt] = *(const short8*)&Bcur[(nbase + nt * 16 + col) * 32 + quad * 8];
    #pragma unroll
    for (int mt = 0; mt < 4; mt++)
      #pragma unroll
      for (int nt = 0; nt < 4; nt++)
        acc[mt][nt] = __builtin_amdgcn_mfma_f32_16x16x32_bf16(af[mt], bfr[nt], acc[mt][nt], 0, 0, 0);

    // ---- cvt A(kw+1) regs -> As[nxt] (DMAs stay in flight) ----
    if (kw < 15) {
      union { short4_t v; __hip_bfloat162 h[2]; } pk;
      pk.h[0] = __float22bfloat162_rn(make_float2(pa.x, pa.y));
      pk.h[1] = __float22bfloat162_rn(make_float2(pa.z, pa.w));
      *(short4_t*)&As[(kw + 1) & 1][awoff] = pk.v;
    }

    // ---- window boundary: drained ops are ~a full window old ----
    asm volatile("s_waitcnt vmcnt(0) lgkmcnt(0)" ::: "memory");
    __builtin_amdgcn_s_barrier();
    __builtin_amdgcn_sched_barrier(0);
  }

  // ---- epilogue: tanh(acc + dec) . w2, reduced over n ----
  // C/D: D[row=quad*4+r][col] => m = mbase+mt*16+quad*4+r, n = nbase+nt*16+col
  const float* decb = dec + b * D_SZ;
  float sums[4][4];
  #pragma unroll
  for (int mt = 0; mt < 4; mt++)
    #pragma unroll
    for (int r = 0; r < 4; r++) sums[mt][r] = 0.f;

  #pragma unroll
  for (int nt = 0; nt < 4; nt++) {
    int n = nbase + nt * 16 + col;
    float dv = decb[n];
    float wv = w2[n];
    #pragma unroll
    for (int mt = 0; mt < 4; mt++)
      #pragma unroll
      for (int r = 0; r < 4; r++)
        sums[mt][r] += fast_tanh(acc[mt][nt][r] + dv) * wv;
  }
  #pragma unroll
  for (int mt = 0; mt < 4; mt++) {
    #pragma unroll
    for (int r = 0; r < 4; r++) {
      float v = sums[mt][r];
      v += __shfl_xor(v, 1, 16);
      v += __shfl_xor(v, 2, 16);
      v += __shfl_xor(v, 4, 16);
      v += __shfl_xor(v, 8, 16);
      if (col == 0) atomicAdd(&s_sc[mbase + mt * 16 + quad * 4 + r], v);  // 8 waves/row
    }
  }
  __syncthreads();
  if (t < 128) scores[b * L_SZ + l0 + t] = s_sc[t];
}

// ---------------------------------------------------------------------------
// Softmax: one WG (1024 threads) per batch row of 2048.
// ---------------------------------------------------------------------------
__global__ __launch_bounds__(1024) void softmax_k(const float* __restrict__ sc,
                                                  float* __restrict__ out) {
  int b = blockIdx.x, t = threadIdx.x;
  int wave = t >> 6, lane = t & 63;
  __shared__ float redm[16], reds[16];
  const float* row = sc + b * L_SZ;
  float v0 = row[t], v1 = row[t + 1024];
  float mx = fmaxf(v0, v1);
  #pragma unroll
  for (int off = 32; off >= 1; off >>= 1) mx = fmaxf(mx, __shfl_xor(mx, off, 64));
  if (lane == 0) redm[wave] = mx;
  __syncthreads();
  float m = redm[0];
  #pragma unroll
  for (int i = 1; i < 16; i++) m = fmaxf(m, redm[i]);
  v0 = __expf(v0 - m);
  v1 = __expf(v1 - m);
  float s = v0 + v1;
  #pragma unroll
  for (int off = 32; off >= 1; off >>= 1) s += __shfl_xor(s, off, 64);
  if (lane == 0) reds[wave] = s;
  __syncthreads();
  float sum = reds[0];
  #pragma unroll
  for (int i = 1; i < 16; i++) sum += reds[i];
  float inv = 1.0f / sum;
  out[b * L_SZ + t]        = v0 * inv;
  out[b * L_SZ + t + 1024] = v1 * inv;
}

extern "C" void kernel_launch(void* const* d_in, const int* in_sizes, int n_in,
                              void* d_out, int out_size, void* d_ws, size_t ws_size,
                              hipStream_t stream) {
  const float* d_hidden = (const float*)d_in[0];   // (32, 2, 512)
  const float* enc      = (const float*)d_in[1];   // (32, 2048, 512)
  const float* W1       = (const float*)d_in[2];   // (1536, 512)
  const float* b1       = (const float*)d_in[3];   // (512,)
  const float* w2       = (const float*)d_in[4];   // (512,)
  float* out = (float*)d_out;                      // (32, 2048)

  char* ws = (char*)d_ws;
  float*    dec = (float*)(ws + WS_DEC_OFF);
  ushort_t* Bt  = (ushort_t*)(ws + WS_BT_OFF);
  float*    sc  = (float*)(ws + WS_SC_OFF);

  prep_k<<<512, 256, 0, stream>>>(d_hidden, W1, b1, dec, Bt);
  main_k<<<dim3(16, 32), 1024, 0, stream>>>(enc, Bt, dec, w2, sc);
  softmax_k<<<32, 1024, 0, stream>>>(sc, out);
}